// Round 9
// baseline (206.037 us; speedup 1.0000x reference)
//
#include <hip/hip_runtime.h>
#include <hip/hip_bf16.h>

static constexpr int B_ = 2;
static constexpr int N_ = 8192;
static constexpr int C_ = 128;
static constexpr int D_ = 128;
static constexpr int K_ = 16;
static constexpr int CAP = 192;   // survivor buffer per query

typedef float f32x4 __attribute__((ext_vector_type(4)));
typedef short s16x8 __attribute__((ext_vector_type(8)));

__device__ __forceinline__ float lrelu(float x) { return fmaxf(x, 0.1f * x); }
__device__ __forceinline__ unsigned short f2bf(float f) {
  __hip_bfloat16 h = __float2bfloat16(f);
  unsigned short u;
  __builtin_memcpy(&u, &h, 2);
  return u;
}
__device__ __forceinline__ float bfl(unsigned int u) { return __uint_as_float(u << 16); }
__device__ __forceinline__ float bfh(unsigned int u) { return __uint_as_float(u & 0xffff0000u); }
__device__ __forceinline__ float rfl(float v) {
  return __uint_as_float((unsigned int)__builtin_amdgcn_readfirstlane((int)__float_as_uint(v)));
}
__device__ __forceinline__ unsigned int mflip(unsigned int x) {
  return x ^ (((unsigned int)(((int)x) >> 31)) | 0x80000000u);
}

// ---------- prep: weights, W_pos SoA, fused bias, cand4 fp32, candA bf16 A-frags, cnorm, cmax ----------
__global__ __launch_bounds__(256) void prep_kernel(
    const float* __restrict__ Wt11, const float* __restrict__ Wt22,
    const float* __restrict__ Wm1, const float* __restrict__ Wm2,
    const float* __restrict__ Wpos, const float* __restrict__ xyz2,
    const float* __restrict__ bt11, const float* __restrict__ bpos,
    float* __restrict__ Wt1T, float* __restrict__ Wt2T,
    unsigned short* __restrict__ w1bf, unsigned short* __restrict__ w2bf,
    float* __restrict__ wpx, float* __restrict__ wpy, float* __restrict__ wpz,
    float* __restrict__ b1c, f32x4* __restrict__ cand4,
    s16x8* __restrict__ candA, float* __restrict__ cnorm, int* __restrict__ cmaxp) {
  int i = blockIdx.x * 256 + threadIdx.x;
  if (i < C_ * D_) {
    int d = i >> 7, c = i & 127;
    Wt1T[c * D_ + d] = Wt11[i];
    Wt2T[c * D_ + d] = Wt22[i];
    w1bf[i] = f2bf(Wm1[i]);
    w2bf[i] = f2bf(Wm2[i]);
    if (i < D_) {
      wpx[i] = Wpos[i * 3 + 0];
      wpy[i] = Wpos[i * 3 + 1];
      wpz[i] = Wpos[i * 3 + 2];
      b1c[i] = bt11[i] + bpos[i];  // fold b_pos into conv1 bias
    }
    // fp32 candidate record: (-x,-y,-z, 0.5|c|^2)
    int bb = i >> 13, m = i & 8191;
    const float* s2 = xyz2 + (size_t)bb * 3 * N_;
    float x = s2[m], y = s2[N_ + m], z = s2[2 * N_ + m];
    f32x4 c4;
    c4[0] = -x; c4[1] = -y; c4[2] = -z;
    c4[3] = 0.5f * (x * x + y * y + z * z);
    cand4[i] = c4;
    cnorm[i] = c4[3];
    // exact per-chip max |coord| for the bf16 error bound
    float am = fmaxf(fmaxf(fabsf(x), fabsf(y)), fabsf(z));
#pragma unroll
    for (int s = 1; s < 64; s <<= 1) am = fmaxf(am, __shfl_xor(am, s, 64));
    if ((threadIdx.x & 63) == 0) atomicMax(cmaxp, __float_as_int(am));
    // bf16 A-fragment tiles: [tile][64 lanes]; lanes 0..15 = rows (k=0..7 data), 16..63 = zeros
#pragma unroll
    for (int rep = 0; rep < 4; ++rep) {
      int idx = i + rep * 16384;          // 65536 slots = 1024 tiles x 64
      int tile = idx >> 6, slot = idx & 63;
      int bb2 = tile >> 9, mt = tile & 511;
      s16x8 frag = (s16x8){0, 0, 0, 0, 0, 0, 0, 0};
      if (slot < 16) {
        int m2 = mt * 16 + slot;
        const float* s2b = xyz2 + (size_t)bb2 * 3 * N_;
        frag[0] = (short)f2bf(-s2b[m2]);
        frag[1] = (short)f2bf(-s2b[N_ + m2]);
        frag[2] = (short)f2bf(-s2b[2 * N_ + m2]);
      }
      candA[(size_t)tile * 64 + slot] = frag;
    }
  }
}

// ---------- conv body: 32-n tile (16 KB LDS), 1x1 conv -> bf16 [b][n][d] ----------
__device__ __forceinline__ void conv_body(
    char* smem, int cbid,
    const float* __restrict__ pts, const float* __restrict__ WT,
    const float* __restrict__ bias, unsigned short* __restrict__ dst) {
  float (*tile)[32] = (float(*)[32])smem;  // 16 KB: [128 c][32 n]
  int b = cbid >> 8;
  int n0 = (cbid & 255) << 5;
  int t = threadIdx.x;
  const float* src = pts + (size_t)b * C_ * N_ + n0;
  for (int i = t; i < C_ * 32; i += 256) {
    int c = i >> 5, nl = i & 31;
    tile[c][nl] = src[(size_t)c * N_ + nl];
  }
  __syncthreads();
  int w = t >> 6, lane = t & 63;
  int nl = lane & 31;
  int d0 = w * 32 + (lane >> 5) * 16;
  float acc[16];
#pragma unroll
  for (int j = 0; j < 16; ++j) acc[j] = 0.f;
  for (int c = 0; c < C_; ++c) {
    float x = tile[c][nl];
    const f32x4* wp = (const f32x4*)(WT + c * D_ + d0);
#pragma unroll
    for (int j = 0; j < 4; ++j) {
      f32x4 wv = wp[j];
#pragma unroll
      for (int q = 0; q < 4; ++q) acc[4 * j + q] += wv[q] * x;
    }
  }
  unsigned short* drow = dst + ((size_t)(b * N_ + n0 + nl)) * D_ + d0;
#pragma unroll
  for (int j8 = 0; j8 < 2; ++j8) {
    uint4 ov;
    unsigned int us[8];
#pragma unroll
    for (int e = 0; e < 8; ++e)
      us[e] = f2bf(acc[8 * j8 + e] + bias[d0 + 8 * j8 + e]);
    ov.x = us[0] | (us[1] << 16);
    ov.y = us[2] | (us[3] << 16);
    ov.z = us[4] | (us[5] << 16);
    ov.w = us[6] | (us[7] << 16);
    *(uint4*)(drow + 8 * j8) = ov;
  }
}

// ---------- knn body: MFMA-scored scan ----------
// block = 16 queries, 4 waves; wave w scans candidate quarter [w*2048,(w+1)*2048)
// LDS: idxbuf u32[16][CAP]           [0, 12288)
//      dmsh  f32[16][64]             [12288, 16384)   (dead after bound)
//      keybuf u64[4][CAP]            [12288, 18432)   (overlay, live in phase 3)
//      thrsh f32[16]                 [18432, 18496)
//      icnt  u32[16]                 [18496, 18560)
__device__ __forceinline__ void knn_body(
    char* smem, int kbid,
    const float* __restrict__ xyz1, const s16x8* __restrict__ candA,
    const float* __restrict__ cnorm, const f32x4* __restrict__ cand4,
    const int* __restrict__ cmaxp, int* __restrict__ idx_out) {
  unsigned int* idxbuf = (unsigned int*)smem;
  float* dmsh = (float*)(smem + 12288);
  unsigned long long* keybuf = (unsigned long long*)(smem + 12288);
  float* thrsh = (float*)(smem + 18432);
  unsigned int* icnt = (unsigned int*)(smem + 18496);

  int b = kbid >> 9;            // 512 blocks per batch
  int q0 = (kbid & 511) << 4;   // 16 queries per block
  int t = threadIdx.x;
  int w = t >> 6, lane = t & 63;
  int grp = lane >> 4, col = lane & 15;

  const float* s1 = xyz1 + (size_t)b * 3 * N_;
  const s16x8* cA = candA + ((size_t)b * 512 + (size_t)w * 128) * 64;
  const float* cnb = cnorm + (size_t)b * N_ + w * 2048;

  if (t < 16) icnt[t] = 0u;

  // B-fragment: lane<16 holds query (q0+lane)'s (qx,qy,qz) in k=0..2; all else zero
  s16x8 qfrag = (s16x8){0, 0, 0, 0, 0, 0, 0, 0};
  if (lane < 16) {
    int q = q0 + lane;
    qfrag[0] = (short)f2bf(s1[q]);
    qfrag[1] = (short)f2bf(s1[N_ + q]);
    qfrag[2] = (short)f2bf(s1[2 * N_ + q]);
  }

  int cno = grp << 2;  // this lane's acc rows = grp*4 .. grp*4+3 within each 16-cand tile
  const f32x4 big = {1e30f, 1e30f, 1e30f, 1e30f};
  f32x4 dminv = big;

  // ---- pass 1: running subset-mins of s~ = 0.5|c|^2 - cq (MFMA), 4-deep prefetch ring ----
  {
    auto P1 = [&](s16x8 af, f32x4 cn) {
      f32x4 acc = __builtin_amdgcn_mfma_f32_16x16x32_bf16(af, qfrag, cn, 0, 0, 0);
#pragma unroll
      for (int r = 0; r < 4; ++r) dminv[r] = fminf(dminv[r], acc[r]);
    };
    s16x8 a0 = cA[lane], a1 = cA[64 + lane], a2 = cA[128 + lane], a3 = cA[192 + lane];
    f32x4 n0 = *(const f32x4*)(cnb + 0 * 16 + cno);
    f32x4 n1 = *(const f32x4*)(cnb + 1 * 16 + cno);
    f32x4 n2 = *(const f32x4*)(cnb + 2 * 16 + cno);
    f32x4 n3 = *(const f32x4*)(cnb + 3 * 16 + cno);
    for (int ct = 0; ct < 124; ct += 4) {
      s16x8 c0 = a0; f32x4 m0 = n0;
      a0 = cA[(ct + 4) * 64 + lane]; n0 = *(const f32x4*)(cnb + (ct + 4) * 16 + cno);
      P1(c0, m0);
      s16x8 c1 = a1; f32x4 m1 = n1;
      a1 = cA[(ct + 5) * 64 + lane]; n1 = *(const f32x4*)(cnb + (ct + 5) * 16 + cno);
      P1(c1, m1);
      s16x8 c2 = a2; f32x4 m2 = n2;
      a2 = cA[(ct + 6) * 64 + lane]; n2 = *(const f32x4*)(cnb + (ct + 6) * 16 + cno);
      P1(c2, m2);
      s16x8 c3 = a3; f32x4 m3 = n3;
      a3 = cA[(ct + 7) * 64 + lane]; n3 = *(const f32x4*)(cnb + (ct + 7) * 16 + cno);
      P1(c3, m3);
    }
    P1(a0, n0); P1(a1, n1); P1(a2, n2); P1(a3, n3);
  }
  // publish 16 subset-mins per (wave, query): slots w*16 + grp*4 + r
  *(f32x4*)(dmsh + col * 64 + w * 16 + cno) = dminv;
  __syncthreads();

  // ---- bound per query: 16th smallest of 64 subset-mins + rigorous bf16 slack ----
  {
    float cmax = __int_as_float(*cmaxp);
    float c1 = cmax * 0.001953125f * 2.1f;  // 2^-9 input-rounding, both operands + margin
    for (int j = 0; j < 4; ++j) {
      int q = 4 * w + j;
      int qg = q0 + q;
      float qxv = rfl(s1[qg]), qyv = rfl(s1[N_ + qg]), qzv = rfl(s1[2 * N_ + qg]);
      unsigned int u = mflip(__float_as_uint(dmsh[q * 64 + lane]));
      unsigned int sel = 0;
      for (int bit = 31; bit >= 0; --bit) {
        unsigned int trial = sel | (1u << bit);
        int c_lt = __popcll(__ballot(u < trial));
        sel = (c_lt < 16) ? trial : sel;
      }
      unsigned int su = sel ^ ((sel & 0x80000000u) ? 0x80000000u : 0xFFFFFFFFu);
      float thr = __uint_as_float(su) + 1e-4f +
                  c1 * (fabsf(qxv) + fabsf(qyv) + fabsf(qzv));
      if (lane == 0) thrsh[q] = thr;
    }
  }
  __syncthreads();

  // ---- pass 2: identical MFMA, append survivors (s~ <= thr) ----
  {
    float thrv = thrsh[col];
    int cbase = w * 2048 + cno;
    auto P2 = [&](s16x8 af, f32x4 cn, int ct) {
      f32x4 acc = __builtin_amdgcn_mfma_f32_16x16x32_bf16(af, qfrag, cn, 0, 0, 0);
      float mn = fminf(fminf(acc[0], acc[1]), fminf(acc[2], acc[3]));
      if (mn <= thrv) {
#pragma unroll
        for (int r = 0; r < 4; ++r) {
          if (acc[r] <= thrv) {
            unsigned int pos = atomicAdd(&icnt[col], 1u);
            if (pos < (unsigned)CAP)
              idxbuf[col * CAP + pos] = (unsigned int)(cbase + ct * 16 + r);
          }
        }
      }
    };
    s16x8 a0 = cA[lane], a1 = cA[64 + lane], a2 = cA[128 + lane], a3 = cA[192 + lane];
    f32x4 n0 = *(const f32x4*)(cnb + 0 * 16 + cno);
    f32x4 n1 = *(const f32x4*)(cnb + 1 * 16 + cno);
    f32x4 n2 = *(const f32x4*)(cnb + 2 * 16 + cno);
    f32x4 n3 = *(const f32x4*)(cnb + 3 * 16 + cno);
    for (int ct = 0; ct < 124; ct += 4) {
      s16x8 c0 = a0; f32x4 m0 = n0;
      a0 = cA[(ct + 4) * 64 + lane]; n0 = *(const f32x4*)(cnb + (ct + 4) * 16 + cno);
      P2(c0, m0, ct);
      s16x8 c1 = a1; f32x4 m1 = n1;
      a1 = cA[(ct + 5) * 64 + lane]; n1 = *(const f32x4*)(cnb + (ct + 5) * 16 + cno);
      P2(c1, m1, ct + 1);
      s16x8 c2 = a2; f32x4 m2 = n2;
      a2 = cA[(ct + 6) * 64 + lane]; n2 = *(const f32x4*)(cnb + (ct + 6) * 16 + cno);
      P2(c2, m2, ct + 2);
      s16x8 c3 = a3; f32x4 m3 = n3;
      a3 = cA[(ct + 7) * 64 + lane]; n3 = *(const f32x4*)(cnb + (ct + 7) * 16 + cno);
      P2(c3, m3, ct + 3);
    }
    P2(a0, n0, 124); P2(a1, n1, 125); P2(a2, n2, 126); P2(a3, n3, 127);
  }
  __syncthreads();

  // ---- phase 3: exact fp32 direct-diff + rank selection; wave w -> queries 4w..4w+3 ----
  const f32x4* cb4 = cand4 + (size_t)b * N_;
  unsigned long long* kb = keybuf + w * CAP;
#pragma unroll 1
  for (int j = 0; j < 4; ++j) {
    int q = 4 * w + j;
    int qg = q0 + q;
    float qxv = rfl(s1[qg]), qyv = rfl(s1[N_ + qg]), qzv = rfl(s1[2 * N_ + qg]);
    int Cq = (int)icnt[q];
    if (Cq > CAP) Cq = CAP;
    unsigned long long keys[3];
    unsigned int idxs[3];
#pragma unroll
    for (int s = 0; s < 3; ++s) {
      int sl = lane + 64 * s;
      bool v = sl < Cq;
      unsigned int iv = v ? idxbuf[q * CAP + sl] : 0u;
      f32x4 c = cb4[iv];
      float tx = c[0] + qxv, ty = c[1] + qyv, tz = c[2] + qzv;
      float d = __builtin_fmaf(tx, tx, __builtin_fmaf(ty, ty, tz * tz));
      keys[s] = v ? ((((unsigned long long)__float_as_uint(d)) << 13) | iv) : ~0ull;
      idxs[s] = iv;
      kb[sl] = keys[s];
    }
    int rank[3] = {0, 0, 0};
    for (int jj = 0; jj < Cq; ++jj) {
      unsigned long long kj = kb[jj];  // uniform-address broadcast read
#pragma unroll
      for (int s = 0; s < 3; ++s) rank[s] += (kj < keys[s]) ? 1 : 0;
    }
    int* dst = idx_out + (((size_t)b * N_ + qg) << 4);
#pragma unroll
    for (int s = 0; s < 3; ++s)
      if (keys[s] != ~0ull && rank[s] < K_) dst[rank[s]] = (int)idxs[s];
  }
}

// ---------- fat kernel: knn (0..1023) || conv1 (1024..1535) || conv2 (1536..2047) ----------
__global__ __launch_bounds__(256, 6) void fat_kernel(
    const float* __restrict__ xyz1, const s16x8* __restrict__ candA,
    const float* __restrict__ cnorm, const f32x4* __restrict__ cand4,
    const int* __restrict__ cmaxp, int* __restrict__ idx_out,
    const float* __restrict__ points1, const float* __restrict__ points2,
    const float* __restrict__ Wt1T, const float* __restrict__ Wt2T,
    const float* __restrict__ b1c, const float* __restrict__ bt22,
    unsigned short* __restrict__ p1b, unsigned short* __restrict__ p2b) {
  __shared__ __align__(16) char smem[18560];
  int bid = blockIdx.x;
  if (bid < 1024) {
    knn_body(smem, bid, xyz1, candA, cnorm, cand4, cmaxp, idx_out);
  } else if (bid < 1536) {
    conv_body(smem, bid - 1024, points1, Wt1T, b1c, p1b);
  } else {
    conv_body(smem, bid - 1536, points2, Wt2T, bt22, p2b);
  }
}

// ---------- fused gather + pos + MLP1 + MLP2 + maxpool + transpose ----------
__global__ __launch_bounds__(256, 4) void fuse_kernel(
    const float* __restrict__ xyz1, const float* __restrict__ xyz2,
    const unsigned short* __restrict__ p1b, const unsigned short* __restrict__ p2b,
    const int* __restrict__ idxb,
    const unsigned short* __restrict__ w1bf, const unsigned short* __restrict__ w2bf,
    const float* __restrict__ wpx, const float* __restrict__ wpy,
    const float* __restrict__ wpz,
    const float* __restrict__ b1, const float* __restrict__ b2,
    float* __restrict__ out) {
  __shared__ unsigned char Abuf[32768];   // h0/h1 bf16 [128][128] XOR-swizzled
  __shared__ float epib[4][8][32];        // per-wave private out tiles (no barrier needed)

  int bid = blockIdx.x;
  int b = bid >> 10;
  int n0 = (bid & 1023) << 3;
  int t = threadIdx.x;
  int wv = t >> 6, lane = t & 63;
  int lrow = lane & 15, lk = lane >> 4;

  // W1 fragments -> registers (wave wv owns dout rows [wv*32, wv*32+32))
  s16x8 wfr[2][4];
#pragma unroll
  for (int j2 = 0; j2 < 2; ++j2)
#pragma unroll
    for (int ks = 0; ks < 4; ++ks) {
      int row = wv * 32 + j2 * 16 + lrow;
      wfr[j2][ks] = *(const s16x8*)(w1bf + row * D_ + ks * 32 + lk * 8);
    }

  // gather + h0 build -> Abuf
  {
    int row = t >> 1, half = t & 1;
    int nl = row >> 4, kn = row & 15;
    int n = n0 + nl;
    int j = idxb[(((size_t)b * N_ + n) << 4) + kn];
    const float* s1 = xyz1 + (size_t)b * 3 * N_;
    const float* s2 = xyz2 + (size_t)b * 3 * N_;
    float dx = s2[j] - s1[n];
    float dy = s2[N_ + j] - s1[N_ + n];
    float dz = s2[2 * N_ + j] - s1[2 * N_ + n];
    const uint4* g2r = (const uint4*)(p2b + ((size_t)(b * N_ + j)) * D_ + half * 64);
    const uint4* p1r = (const uint4*)(p1b + ((size_t)(b * N_ + n)) * D_ + half * 64);
    int rswz = (row & 7) << 4;
#pragma unroll
    for (int it = 0; it < 8; ++it) {
      int dbase = half * 64 + it * 8;
      uint4 gv = g2r[it];
      uint4 pv = p1r[it];
      float g[8] = {bfl(gv.x), bfh(gv.x), bfl(gv.y), bfh(gv.y),
                    bfl(gv.z), bfh(gv.z), bfl(gv.w), bfh(gv.w)};
      float pp[8] = {bfl(pv.x), bfh(pv.x), bfl(pv.y), bfh(pv.y),
                     bfl(pv.z), bfh(pv.z), bfl(pv.w), bfh(pv.w)};
      f32x4 wxa = *(const f32x4*)(wpx + dbase);
      f32x4 wxb = *(const f32x4*)(wpx + dbase + 4);
      f32x4 wya = *(const f32x4*)(wpy + dbase);
      f32x4 wyb = *(const f32x4*)(wpy + dbase + 4);
      f32x4 wza = *(const f32x4*)(wpz + dbase);
      f32x4 wzb = *(const f32x4*)(wpz + dbase + 4);
      unsigned int us[8];
#pragma unroll
      for (int q = 0; q < 8; ++q) {
        float wx = q < 4 ? wxa[q] : wxb[q - 4];
        float wy = q < 4 ? wya[q] : wyb[q - 4];
        float wz = q < 4 ? wza[q] : wzb[q - 4];
        float v = __builtin_fmaf(wx, dx, __builtin_fmaf(wy, dy,
                  __builtin_fmaf(wz, dz, g[q] + pp[q])));
        us[q] = f2bf(lrelu(v));
      }
      uint4 val4;
      val4.x = us[0] | (us[1] << 16);
      val4.y = us[2] | (us[3] << 16);
      val4.z = us[4] | (us[5] << 16);
      val4.w = us[6] | (us[7] << 16);
      int off = (row << 8) + (dbase << 1);
      *(uint4*)(Abuf + (off ^ rswz)) = val4;
    }
  }
  __syncthreads();

  const f32x4 fzero = {0.f, 0.f, 0.f, 0.f};
  f32x4 acc[8][2];
#pragma unroll
  for (int m = 0; m < 8; ++m) { acc[m][0] = fzero; acc[m][1] = fzero; }

  // layer 1
#pragma unroll
  for (int ks = 0; ks < 4; ++ks) {
#pragma unroll
    for (int m = 0; m < 8; ++m) {
      int rw = m * 16 + lrow;
      int off = (rw << 8) + (ks << 6) + (lk << 4);
      s16x8 afr = *(const s16x8*)(Abuf + (off ^ ((rw & 7) << 4)));
      acc[m][0] = __builtin_amdgcn_mfma_f32_16x16x32_bf16(afr, wfr[0][ks], acc[m][0], 0, 0, 0);
      acc[m][1] = __builtin_amdgcn_mfma_f32_16x16x32_bf16(afr, wfr[1][ks], acc[m][1], 0, 0, 0);
    }
  }
  __syncthreads();  // all layer-1 Abuf reads done

  // W2 frags (issue early; latency hides under h1 conversion VALU)
#pragma unroll
  for (int j2 = 0; j2 < 2; ++j2)
#pragma unroll
    for (int ks = 0; ks < 4; ++ks) {
      int row = wv * 32 + j2 * 16 + lrow;
      wfr[j2][ks] = *(const s16x8*)(w2bf + row * D_ + ks * 32 + lk * 8);
    }

  // h1 -> Abuf
  {
    float bias1[2];
    bias1[0] = b1[wv * 32 + lrow];
    bias1[1] = b1[wv * 32 + 16 + lrow];
#pragma unroll
    for (int m = 0; m < 8; ++m)
#pragma unroll
      for (int j2 = 0; j2 < 2; ++j2)
#pragma unroll
        for (int r = 0; r < 4; ++r) {
          int rw = m * 16 + lk * 4 + r;
          int col = wv * 32 + j2 * 16 + lrow;
          unsigned short hv = f2bf(lrelu(acc[m][j2][r] + bias1[j2]));
          int off = (rw << 8) + (col << 1);
          *(unsigned short*)(Abuf + (off ^ ((rw & 7) << 4))) = hv;
        }
  }
  __syncthreads();

#pragma unroll
  for (int m = 0; m < 8; ++m) { acc[m][0] = fzero; acc[m][1] = fzero; }

  // layer 2
#pragma unroll
  for (int ks = 0; ks < 4; ++ks) {
#pragma unroll
    for (int m = 0; m < 8; ++m) {
      int rw = m * 16 + lrow;
      int off = (rw << 8) + (ks << 6) + (lk << 4);
      s16x8 afr = *(const s16x8*)(Abuf + (off ^ ((rw & 7) << 4)));
      acc[m][0] = __builtin_amdgcn_mfma_f32_16x16x32_bf16(afr, wfr[0][ks], acc[m][0], 0, 0, 0);
      acc[m][1] = __builtin_amdgcn_mfma_f32_16x16x32_bf16(afr, wfr[1][ks], acc[m][1], 0, 0, 0);
    }
  }

  // epilogue: bias + leaky + max over k -> per-wave LDS tile -> global (no barriers)
  float bias2[2];
  bias2[0] = b2[wv * 32 + lrow];
  bias2[1] = b2[wv * 32 + 16 + lrow];
#pragma unroll
  for (int m = 0; m < 8; ++m) {
#pragma unroll
    for (int j2 = 0; j2 < 2; ++j2) {
      float mx = -1e30f;
#pragma unroll
      for (int r = 0; r < 4; ++r) mx = fmaxf(mx, lrelu(acc[m][j2][r] + bias2[j2]));
      mx = fmaxf(mx, __shfl_xor(mx, 16, 64));
      mx = fmaxf(mx, __shfl_xor(mx, 32, 64));
      if (lk == 0) epib[wv][m][j2 * 16 + lrow] = mx;
    }
  }
  // wave-local transpose read (compiler inserts lgkmcnt; same wave wrote it)
  {
    int dl = lane >> 1, nh = lane & 1;
    f32x4 o;
#pragma unroll
    for (int i2 = 0; i2 < 4; ++i2) o[i2] = epib[wv][nh * 4 + i2][dl];
    *(f32x4*)(out + ((size_t)(b * D_ + wv * 32 + dl)) * N_ + n0 + nh * 4) = o;
  }
}

extern "C" void kernel_launch(void* const* d_in, const int* in_sizes, int n_in,
                              void* d_out, int out_size, void* d_ws, size_t ws_size,
                              hipStream_t stream) {
  (void)in_sizes; (void)n_in; (void)out_size; (void)ws_size;
  const float* xyz1    = (const float*)d_in[0];
  const float* xyz2    = (const float*)d_in[1];
  const float* points1 = (const float*)d_in[2];
  const float* points2 = (const float*)d_in[3];
  const float* W_t11   = (const float*)d_in[4];
  const float* b_t11   = (const float*)d_in[5];
  const float* W_t22   = (const float*)d_in[6];
  const float* b_t22   = (const float*)d_in[7];
  const float* W_pos   = (const float*)d_in[8];
  const float* b_pos   = (const float*)d_in[9];
  const float* W_mlp1  = (const float*)d_in[10];
  const float* b_mlp1  = (const float*)d_in[11];
  const float* W_mlp2  = (const float*)d_in[12];
  const float* b_mlp2  = (const float*)d_in[13];
  float* out = (float*)d_out;

  char* ws = (char*)d_ws;
  unsigned short* p1b  = (unsigned short*)(ws);                 // 4 MB
  unsigned short* p2b  = (unsigned short*)(ws + 4194304);       // 4 MB
  float* Wt1T          = (float*)(ws + 8388608);                // 64 KB
  float* Wt2T          = (float*)(ws + 8454144);                // 64 KB
  unsigned short* w1bf = (unsigned short*)(ws + 8519680);       // 32 KB
  unsigned short* w2bf = (unsigned short*)(ws + 8552448);       // 32 KB
  float* wpx           = (float*)(ws + 8585216);                // 512 B
  float* wpy           = (float*)(ws + 8585728);
  float* wpz           = (float*)(ws + 8586240);
  f32x4* cand4         = (f32x4*)(ws + 8586752);                // 256 KB
  int* idxws           = (int*)(ws + 8848896);                  // 1 MB
  float* b1c           = (float*)(ws + 9897472);                // 512 B
  s16x8* candA         = (s16x8*)(ws + 9898496);                // 1 MB (1024 tiles x 64 x 16B)
  float* cnorm         = (float*)(ws + 10947072);               // 64 KB
  int* cmaxp           = (int*)(ws + 11012608);                 // 4 B

  hipMemsetAsync(cmaxp, 0, 4, stream);
  prep_kernel<<<64, 256, 0, stream>>>(W_t11, W_t22, W_mlp1, W_mlp2, W_pos, xyz2,
                                      b_t11, b_pos,
                                      Wt1T, Wt2T, w1bf, w2bf, wpx, wpy, wpz,
                                      b1c, cand4, candA, cnorm, cmaxp);
  fat_kernel<<<2048, 256, 0, stream>>>(xyz1, candA, cnorm, cand4, cmaxp, idxws,
                                       points1, points2, Wt1T, Wt2T,
                                       b1c, b_t22, p1b, p2b);
  fuse_kernel<<<B_ * 1024, 256, 0, stream>>>(xyz1, xyz2, p1b, p2b, idxws,
                                             w1bf, w2bf, wpx, wpy, wpz,
                                             b_mlp1, b_mlp2, out);
}

// Round 10
// 155.594 us; speedup vs baseline: 1.3242x; 1.3242x over previous
//
#include <hip/hip_runtime.h>
#include <hip/hip_bf16.h>

static constexpr int B_ = 2;
static constexpr int N_ = 8192;
static constexpr int C_ = 128;
static constexpr int D_ = 128;
static constexpr int K_ = 16;

typedef float f32x4 __attribute__((ext_vector_type(4)));
typedef short s16x8 __attribute__((ext_vector_type(8)));

__device__ __forceinline__ float lrelu(float x) { return fmaxf(x, 0.1f * x); }
__device__ __forceinline__ unsigned short f2bf(float f) {
  __hip_bfloat16 h = __float2bfloat16(f);
  unsigned short u;
  __builtin_memcpy(&u, &h, 2);
  return u;
}
__device__ __forceinline__ float bfl(unsigned int u) { return __uint_as_float(u << 16); }
__device__ __forceinline__ float bfh(unsigned int u) { return __uint_as_float(u & 0xffff0000u); }
__device__ __forceinline__ float rfl(float v) {
  return __uint_as_float((unsigned int)__builtin_amdgcn_readfirstlane((int)__float_as_uint(v)));
}
__device__ __forceinline__ unsigned int mflip(unsigned int x) {
  return x ^ (((unsigned int)(((int)x) >> 31)) | 0x80000000u);
}

// ---------- prep: transposes, bf16 weights, W_pos SoA, fused bias, negated cand4 ----------
__global__ __launch_bounds__(256) void prep_kernel(
    const float* __restrict__ Wt11, const float* __restrict__ Wt22,
    const float* __restrict__ Wm1, const float* __restrict__ Wm2,
    const float* __restrict__ Wpos, const float* __restrict__ xyz2,
    const float* __restrict__ bt11, const float* __restrict__ bpos,
    float* __restrict__ Wt1T, float* __restrict__ Wt2T,
    unsigned short* __restrict__ w1bf, unsigned short* __restrict__ w2bf,
    float* __restrict__ wpx, float* __restrict__ wpy, float* __restrict__ wpz,
    float* __restrict__ b1c, f32x4* __restrict__ cand4) {
  int i = blockIdx.x * 256 + threadIdx.x;
  if (i < C_ * D_) {
    int d = i >> 7, c = i & 127;
    Wt1T[c * D_ + d] = Wt11[i];
    Wt2T[c * D_ + d] = Wt22[i];
    w1bf[i] = f2bf(Wm1[i]);
    w2bf[i] = f2bf(Wm2[i]);
    if (i < D_) {
      wpx[i] = Wpos[i * 3 + 0];
      wpy[i] = Wpos[i * 3 + 1];
      wpz[i] = Wpos[i * 3 + 2];
      b1c[i] = bt11[i] + bpos[i];  // fold b_pos into conv1 bias
    }
    int bb = i >> 13, m = i & 8191;
    const float* s2 = xyz2 + (size_t)bb * 3 * N_;
    float x = s2[m], y = s2[N_ + m], z = s2[2 * N_ + m];
    f32x4 c4;
    c4[0] = -x; c4[1] = -y; c4[2] = -z;
    c4[3] = 0.5f * (x * x + y * y + z * z);
    cand4[(size_t)bb * N_ + m] = c4;
  }
}

// ---------- conv body: 32-n tile (16 KB LDS), 1x1 conv -> bf16 [b][n][d] ----------
__device__ __forceinline__ void conv_body(
    char* smem, int cbid,
    const float* __restrict__ pts, const float* __restrict__ WT,
    const float* __restrict__ bias, unsigned short* __restrict__ dst) {
  float (*tile)[32] = (float(*)[32])smem;  // 16 KB: [128 c][32 n]
  int b = cbid >> 8;
  int n0 = (cbid & 255) << 5;
  int t = threadIdx.x;
  const float* src = pts + (size_t)b * C_ * N_ + n0;
  for (int i = t; i < C_ * 32; i += 256) {
    int c = i >> 5, nl = i & 31;
    tile[c][nl] = src[(size_t)c * N_ + nl];
  }
  __syncthreads();
  int w = t >> 6, lane = t & 63;
  int nl = lane & 31;
  int d0 = w * 32 + (lane >> 5) * 16;
  float acc[16];
#pragma unroll
  for (int j = 0; j < 16; ++j) acc[j] = 0.f;
  for (int c = 0; c < C_; ++c) {
    float x = tile[c][nl];
    const f32x4* wp = (const f32x4*)(WT + c * D_ + d0);
#pragma unroll
    for (int j = 0; j < 4; ++j) {
      f32x4 wv = wp[j];
#pragma unroll
      for (int q = 0; q < 4; ++q) acc[4 * j + q] += wv[q] * x;
    }
  }
  unsigned short* drow = dst + ((size_t)(b * N_ + n0 + nl)) * D_ + d0;
#pragma unroll
  for (int j8 = 0; j8 < 2; ++j8) {
    uint4 ov;
    unsigned int us[8];
#pragma unroll
    for (int e = 0; e < 8; ++e)
      us[e] = f2bf(acc[8 * j8 + e] + bias[d0 + 8 * j8 + e]);
    ov.x = us[0] | (us[1] << 16);
    ov.y = us[2] | (us[3] << 16);
    ov.z = us[4] | (us[5] << 16);
    ov.w = us[6] | (us[7] << 16);
    *(uint4*)(drow + 8 * j8) = ov;
  }
}

// ---------- knn body: 16 q/block, Q=8/wave x 2 cand-halves, shared bound, atomic append ----------
// LDS: [0,8192)  dmsh float[2][2][8][64]  (lane-mins; dead after thr)  -- overlaid by
//                keybuf u64[4][128] (4 KB) in phase 3
//      [8192,16384) idxbuf u32[2][8][128]
//      [16384,16448) icnt u32[2][8]
__device__ __forceinline__ void knn_body(
    char* smem, int kbid,
    const float* __restrict__ xyz1, const f32x4* __restrict__ cand4,
    int* __restrict__ idx_out) {
  float (*dmsh)[2][8][64] = (float(*)[2][8][64])smem;
  unsigned long long (*keybuf)[128] = (unsigned long long(*)[128])smem;
  unsigned int (*idxbuf)[8][128] = (unsigned int(*)[8][128])(smem + 8192);
  unsigned int (*icnt)[8] = (unsigned int(*)[8])(smem + 16384);

  int b = kbid >> 9;            // 512 blocks per batch
  int q0 = (kbid & 511) << 4;   // 16 queries per block
  int t = threadIdx.x;
  int w = t >> 6, lane = t & 63;
  int g = w >> 1, h = w & 1;    // query-group, candidate-half
  int qbase = q0 + (g << 3);    // 8 queries per wave-pair

  const float* s1 = xyz1 + (size_t)b * 3 * N_;
  const f32x4* cbf = cand4 + (size_t)b * N_;   // full candidate array
  const f32x4* cb = cbf + (h << 12);           // this wave's half (4096)

  if (t < 16) icnt[t >> 3][t & 7] = 0u;  // ordered by the pass-1 barrier

  float qx[8], qy[8], qz[8], dmin[8];
#pragma unroll
  for (int qq = 0; qq < 8; ++qq) {
    int q = qbase + qq;
    qx[qq] = rfl(s1[q]);
    qy[qq] = rfl(s1[N_ + q]);
    qz[qq] = rfl(s1[2 * N_ + q]);
    dmin[qq] = 1e30f;
  }

  // pass 1: per-lane min of s = 0.5|c|^2 - c.q over this half, 4-deep prefetch ring
  {
    f32x4 p0 = cb[lane], p1 = cb[64 + lane], p2 = cb[128 + lane], p3 = cb[192 + lane];
    auto proc1 = [&](f32x4 c) {
#pragma unroll
      for (int qq = 0; qq < 8; ++qq) {
        float s = __builtin_fmaf(c[0], qx[qq],
                  __builtin_fmaf(c[1], qy[qq],
                  __builtin_fmaf(c[2], qz[qq], c[3])));
        dmin[qq] = fminf(dmin[qq], s);
      }
    };
    for (int i = 0; i < 60; i += 4) {
      f32x4 c0 = p0; p0 = cb[((i + 4) << 6) + lane]; proc1(c0);
      f32x4 c1 = p1; p1 = cb[((i + 5) << 6) + lane]; proc1(c1);
      f32x4 c2 = p2; p2 = cb[((i + 6) << 6) + lane]; proc1(c2);
      f32x4 c3 = p3; p3 = cb[((i + 7) << 6) + lane]; proc1(c3);
    }
    proc1(p0); proc1(p1); proc1(p2); proc1(p3);
  }

  // share lane-mins across the wave-pair
#pragma unroll
  for (int qq = 0; qq < 8; ++qq) dmsh[g][h][qq][lane] = dmin[qq];
  __syncthreads();

  // bound: 16th smallest of the 128 union lane-mins (2 values/lane), radix ballot search
  float thr[8];
#pragma unroll 1
  for (int qq = 0; qq < 8; ++qq) {
    unsigned int u0 = mflip(__float_as_uint(dmin[qq]));
    unsigned int u1 = mflip(__float_as_uint(dmsh[g][1 ^ h][qq][lane]));
    unsigned int sel = 0;
    for (int bit = 31; bit >= 0; --bit) {
      unsigned int trial = sel | (1u << bit);
      int c_lt = __popcll(__ballot(u0 < trial)) + __popcll(__ballot(u1 < trial));
      sel = (c_lt < 16) ? trial : sel;
    }
    unsigned int su = sel ^ ((sel & 0x80000000u) ? 0x80000000u : 0xFFFFFFFFu);
    float tf = __uint_as_float(su);
    thr[qq] = tf + (1e-4f + 4e-7f * fabsf(tf));
  }
  float thrmax = thr[0];
#pragma unroll
  for (int qq = 1; qq < 8; ++qq) thrmax = fmaxf(thrmax, thr[qq]);

  // pass 2: append survivors (s <= thr) via shared LDS atomics.
  // Common path is wave-uniform: min8(s) vs thrmax + __any -> one scalar branch.
  {
    f32x4 p0 = cb[lane], p1 = cb[64 + lane], p2 = cb[128 + lane], p3 = cb[192 + lane];
    int mo = (h << 12) + lane;
    auto proc2 = [&](f32x4 c, int m) {
      float s[8];
#pragma unroll
      for (int qq = 0; qq < 8; ++qq)
        s[qq] = __builtin_fmaf(c[0], qx[qq],
                __builtin_fmaf(c[1], qy[qq],
                __builtin_fmaf(c[2], qz[qq], c[3])));
      float mn = fminf(fminf(fminf(s[0], s[1]), fminf(s[2], s[3])),
                       fminf(fminf(s[4], s[5]), fminf(s[6], s[7])));
      if (__any(mn <= thrmax)) {
#pragma unroll
        for (int qq = 0; qq < 8; ++qq) {
          if (s[qq] <= thr[qq]) {
            unsigned int pos = atomicAdd(&icnt[g][qq], 1u);
            if (pos < 128u) idxbuf[g][qq][pos] = (unsigned int)m;
          }
        }
      }
    };
    for (int i = 0; i < 60; i += 4) {
      f32x4 c0 = p0; p0 = cb[((i + 4) << 6) + lane]; proc2(c0, mo + (i << 6));
      f32x4 c1 = p1; p1 = cb[((i + 5) << 6) + lane]; proc2(c1, mo + ((i + 1) << 6));
      f32x4 c2 = p2; p2 = cb[((i + 6) << 6) + lane]; proc2(c2, mo + ((i + 2) << 6));
      f32x4 c3 = p3; p3 = cb[((i + 7) << 6) + lane]; proc2(c3, mo + ((i + 3) << 6));
    }
    proc2(p0, mo + (60 << 6));
    proc2(p1, mo + (61 << 6));
    proc2(p2, mo + (62 << 6));
    proc2(p3, mo + (63 << 6));
  }
  __syncthreads();  // appends done; dmsh dead -> keybuf overlay live

  // phase 3: wave w handles block-queries 4w..4w+3; exact dist + rank select
#pragma unroll 1
  for (int j = 0; j < 4; ++j) {
    int wq = (w << 2) + j;
    int g2 = wq >> 3, qq2 = wq & 7;
    int q = q0 + wq;
    float qx2 = rfl(s1[q]);
    float qy2 = rfl(s1[N_ + q]);
    float qz2 = rfl(s1[2 * N_ + q]);
    int Cq = (int)icnt[g2][qq2];
    if (Cq > 128) Cq = 128;
    bool v0 = lane < Cq;
    unsigned int i0v = v0 ? idxbuf[g2][qq2][lane] : 0u;
    f32x4 c0 = cbf[i0v];
    float t0x = c0[0] + qx2, t0y = c0[1] + qy2, t0z = c0[2] + qz2;
    float d0 = __builtin_fmaf(t0x, t0x, __builtin_fmaf(t0y, t0y, t0z * t0z));
    unsigned long long key0 =
        v0 ? ((((unsigned long long)__float_as_uint(d0)) << 13) | i0v) : ~0ull;
    unsigned long long key1 = ~0ull;
    unsigned int i1v = 0;
    if (Cq > 64) {  // wave-uniform
      bool v1 = (lane + 64) < Cq;
      i1v = v1 ? idxbuf[g2][qq2][lane + 64] : 0u;
      f32x4 c1 = cbf[i1v];
      float t1x = c1[0] + qx2, t1y = c1[1] + qy2, t1z = c1[2] + qz2;
      float d1 = __builtin_fmaf(t1x, t1x, __builtin_fmaf(t1y, t1y, t1z * t1z));
      key1 = v1 ? ((((unsigned long long)__float_as_uint(d1)) << 13) | i1v) : ~0ull;
    }
    keybuf[w][lane] = key0;
    keybuf[w][lane + 64] = key1;
    int rank0 = 0, rank1 = 0;
    for (int j2 = 0; j2 < Cq; ++j2) {
      unsigned long long kj = keybuf[w][j2];  // uniform-address broadcast read
      rank0 += (kj < key0) ? 1 : 0;
      rank1 += (kj < key1) ? 1 : 0;
    }
    int* dst = idx_out + (((size_t)b * N_ + q) << 4);
    if (v0 && rank0 < K_) dst[rank0] = (int)i0v;
    if (key1 != ~0ull && rank1 < K_) dst[rank1] = (int)i1v;
  }
}

// ---------- fat kernel: knn (0..1023) || conv1 (1024..1535) || conv2 (1536..2047) ----------
__global__ __launch_bounds__(256, 8) void fat_kernel(
    const float* __restrict__ xyz1, const f32x4* __restrict__ cand4,
    int* __restrict__ idx_out,
    const float* __restrict__ points1, const float* __restrict__ points2,
    const float* __restrict__ Wt1T, const float* __restrict__ Wt2T,
    const float* __restrict__ b1c, const float* __restrict__ bt22,
    unsigned short* __restrict__ p1b, unsigned short* __restrict__ p2b) {
  __shared__ __align__(16) char smem[16448];
  int bid = blockIdx.x;
  if (bid < 1024) {
    knn_body(smem, bid, xyz1, cand4, idx_out);
  } else if (bid < 1536) {
    conv_body(smem, bid - 1024, points1, Wt1T, b1c, p1b);
  } else {
    conv_body(smem, bid - 1536, points2, Wt2T, bt22, p2b);
  }
}

// ---------- fused gather + pos + MLP1 + MLP2 + maxpool + transpose ----------
__global__ __launch_bounds__(256, 4) void fuse_kernel(
    const float* __restrict__ xyz1, const float* __restrict__ xyz2,
    const unsigned short* __restrict__ p1b, const unsigned short* __restrict__ p2b,
    const int* __restrict__ idxb,
    const unsigned short* __restrict__ w1bf, const unsigned short* __restrict__ w2bf,
    const float* __restrict__ wpx, const float* __restrict__ wpy,
    const float* __restrict__ wpz,
    const float* __restrict__ b1, const float* __restrict__ b2,
    float* __restrict__ out) {
  __shared__ unsigned char Abuf[32768];   // h0/h1 bf16 [128][128] XOR-swizzled
  __shared__ float epib[4][8][32];        // per-wave private out tiles (no barrier needed)

  int bid = blockIdx.x;
  int b = bid >> 10;
  int n0 = (bid & 1023) << 3;
  int t = threadIdx.x;
  int wv = t >> 6, lane = t & 63;
  int lrow = lane & 15, lk = lane >> 4;

  // W1 fragments -> registers (wave wv owns dout rows [wv*32, wv*32+32))
  s16x8 wfr[2][4];
#pragma unroll
  for (int j2 = 0; j2 < 2; ++j2)
#pragma unroll
    for (int ks = 0; ks < 4; ++ks) {
      int row = wv * 32 + j2 * 16 + lrow;
      wfr[j2][ks] = *(const s16x8*)(w1bf + row * D_ + ks * 32 + lk * 8);
    }

  // gather + h0 build -> Abuf
  {
    int row = t >> 1, half = t & 1;
    int nl = row >> 4, kn = row & 15;
    int n = n0 + nl;
    int j = idxb[(((size_t)b * N_ + n) << 4) + kn];
    const float* s1 = xyz1 + (size_t)b * 3 * N_;
    const float* s2 = xyz2 + (size_t)b * 3 * N_;
    float dx = s2[j] - s1[n];
    float dy = s2[N_ + j] - s1[N_ + n];
    float dz = s2[2 * N_ + j] - s1[2 * N_ + n];
    const uint4* g2r = (const uint4*)(p2b + ((size_t)(b * N_ + j)) * D_ + half * 64);
    const uint4* p1r = (const uint4*)(p1b + ((size_t)(b * N_ + n)) * D_ + half * 64);
    int rswz = (row & 7) << 4;
#pragma unroll
    for (int it = 0; it < 8; ++it) {
      int dbase = half * 64 + it * 8;
      uint4 gv = g2r[it];
      uint4 pv = p1r[it];
      float g[8] = {bfl(gv.x), bfh(gv.x), bfl(gv.y), bfh(gv.y),
                    bfl(gv.z), bfh(gv.z), bfl(gv.w), bfh(gv.w)};
      float pp[8] = {bfl(pv.x), bfh(pv.x), bfl(pv.y), bfh(pv.y),
                     bfl(pv.z), bfh(pv.z), bfl(pv.w), bfh(pv.w)};
      f32x4 wxa = *(const f32x4*)(wpx + dbase);
      f32x4 wxb = *(const f32x4*)(wpx + dbase + 4);
      f32x4 wya = *(const f32x4*)(wpy + dbase);
      f32x4 wyb = *(const f32x4*)(wpy + dbase + 4);
      f32x4 wza = *(const f32x4*)(wpz + dbase);
      f32x4 wzb = *(const f32x4*)(wpz + dbase + 4);
      unsigned int us[8];
#pragma unroll
      for (int q = 0; q < 8; ++q) {
        float wx = q < 4 ? wxa[q] : wxb[q - 4];
        float wy = q < 4 ? wya[q] : wyb[q - 4];
        float wz = q < 4 ? wza[q] : wzb[q - 4];
        float v = __builtin_fmaf(wx, dx, __builtin_fmaf(wy, dy,
                  __builtin_fmaf(wz, dz, g[q] + pp[q])));
        us[q] = f2bf(lrelu(v));
      }
      uint4 val4;
      val4.x = us[0] | (us[1] << 16);
      val4.y = us[2] | (us[3] << 16);
      val4.z = us[4] | (us[5] << 16);
      val4.w = us[6] | (us[7] << 16);
      int off = (row << 8) + (dbase << 1);
      *(uint4*)(Abuf + (off ^ rswz)) = val4;
    }
  }
  __syncthreads();

  const f32x4 fzero = {0.f, 0.f, 0.f, 0.f};
  f32x4 acc[8][2];
#pragma unroll
  for (int m = 0; m < 8; ++m) { acc[m][0] = fzero; acc[m][1] = fzero; }

  // layer 1
#pragma unroll
  for (int ks = 0; ks < 4; ++ks) {
#pragma unroll
    for (int m = 0; m < 8; ++m) {
      int rw = m * 16 + lrow;
      int off = (rw << 8) + (ks << 6) + (lk << 4);
      s16x8 afr = *(const s16x8*)(Abuf + (off ^ ((rw & 7) << 4)));
      acc[m][0] = __builtin_amdgcn_mfma_f32_16x16x32_bf16(afr, wfr[0][ks], acc[m][0], 0, 0, 0);
      acc[m][1] = __builtin_amdgcn_mfma_f32_16x16x32_bf16(afr, wfr[1][ks], acc[m][1], 0, 0, 0);
    }
  }
  __syncthreads();  // all layer-1 Abuf reads done

  // W2 frags (issue early; latency hides under h1 conversion VALU)
#pragma unroll
  for (int j2 = 0; j2 < 2; ++j2)
#pragma unroll
    for (int ks = 0; ks < 4; ++ks) {
      int row = wv * 32 + j2 * 16 + lrow;
      wfr[j2][ks] = *(const s16x8*)(w2bf + row * D_ + ks * 32 + lk * 8);
    }

  // h1 -> Abuf
  {
    float bias1[2];
    bias1[0] = b1[wv * 32 + lrow];
    bias1[1] = b1[wv * 32 + 16 + lrow];
#pragma unroll
    for (int m = 0; m < 8; ++m)
#pragma unroll
      for (int j2 = 0; j2 < 2; ++j2)
#pragma unroll
        for (int r = 0; r < 4; ++r) {
          int rw = m * 16 + lk * 4 + r;
          int col = wv * 32 + j2 * 16 + lrow;
          unsigned short hv = f2bf(lrelu(acc[m][j2][r] + bias1[j2]));
          int off = (rw << 8) + (col << 1);
          *(unsigned short*)(Abuf + (off ^ ((rw & 7) << 4))) = hv;
        }
  }
  __syncthreads();

#pragma unroll
  for (int m = 0; m < 8; ++m) { acc[m][0] = fzero; acc[m][1] = fzero; }

  // layer 2
#pragma unroll
  for (int ks = 0; ks < 4; ++ks) {
#pragma unroll
    for (int m = 0; m < 8; ++m) {
      int rw = m * 16 + lrow;
      int off = (rw << 8) + (ks << 6) + (lk << 4);
      s16x8 afr = *(const s16x8*)(Abuf + (off ^ ((rw & 7) << 4)));
      acc[m][0] = __builtin_amdgcn_mfma_f32_16x16x32_bf16(afr, wfr[0][ks], acc[m][0], 0, 0, 0);
      acc[m][1] = __builtin_amdgcn_mfma_f32_16x16x32_bf16(afr, wfr[1][ks], acc[m][1], 0, 0, 0);
    }
  }

  // epilogue: bias + leaky + max over k -> per-wave LDS tile -> global (no barriers)
  float bias2[2];
  bias2[0] = b2[wv * 32 + lrow];
  bias2[1] = b2[wv * 32 + 16 + lrow];
#pragma unroll
  for (int m = 0; m < 8; ++m) {
#pragma unroll
    for (int j2 = 0; j2 < 2; ++j2) {
      float mx = -1e30f;
#pragma unroll
      for (int r = 0; r < 4; ++r) mx = fmaxf(mx, lrelu(acc[m][j2][r] + bias2[j2]));
      mx = fmaxf(mx, __shfl_xor(mx, 16, 64));
      mx = fmaxf(mx, __shfl_xor(mx, 32, 64));
      if (lk == 0) epib[wv][m][j2 * 16 + lrow] = mx;
    }
  }
  // wave-local transpose read (compiler inserts lgkmcnt; same wave wrote it)
  {
    int dl = lane >> 1, nh = lane & 1;
    f32x4 o;
#pragma unroll
    for (int i2 = 0; i2 < 4; ++i2) o[i2] = epib[wv][nh * 4 + i2][dl];
    *(f32x4*)(out + ((size_t)(b * D_ + wv * 32 + dl)) * N_ + n0 + nh * 4) = o;
  }
}

extern "C" void kernel_launch(void* const* d_in, const int* in_sizes, int n_in,
                              void* d_out, int out_size, void* d_ws, size_t ws_size,
                              hipStream_t stream) {
  (void)in_sizes; (void)n_in; (void)out_size; (void)ws_size;
  const float* xyz1    = (const float*)d_in[0];
  const float* xyz2    = (const float*)d_in[1];
  const float* points1 = (const float*)d_in[2];
  const float* points2 = (const float*)d_in[3];
  const float* W_t11   = (const float*)d_in[4];
  const float* b_t11   = (const float*)d_in[5];
  const float* W_t22   = (const float*)d_in[6];
  const float* b_t22   = (const float*)d_in[7];
  const float* W_pos   = (const float*)d_in[8];
  const float* b_pos   = (const float*)d_in[9];
  const float* W_mlp1  = (const float*)d_in[10];
  const float* b_mlp1  = (const float*)d_in[11];
  const float* W_mlp2  = (const float*)d_in[12];
  const float* b_mlp2  = (const float*)d_in[13];
  float* out = (float*)d_out;

  char* ws = (char*)d_ws;
  unsigned short* p1b  = (unsigned short*)(ws);                 // 4 MB
  unsigned short* p2b  = (unsigned short*)(ws + 4194304);       // 4 MB
  float* Wt1T          = (float*)(ws + 8388608);                // 64 KB
  float* Wt2T          = (float*)(ws + 8454144);                // 64 KB
  unsigned short* w1bf = (unsigned short*)(ws + 8519680);       // 32 KB
  unsigned short* w2bf = (unsigned short*)(ws + 8552448);       // 32 KB
  float* wpx           = (float*)(ws + 8585216);                // 512 B
  float* wpy           = (float*)(ws + 8585728);
  float* wpz           = (float*)(ws + 8586240);
  f32x4* cand4         = (f32x4*)(ws + 8586752);                // 256 KB
  int* idxws           = (int*)(ws + 8848896);                  // 1 MB
  float* b1c           = (float*)(ws + 9897472);                // 512 B

  prep_kernel<<<64, 256, 0, stream>>>(W_t11, W_t22, W_mlp1, W_mlp2, W_pos, xyz2,
                                      b_t11, b_pos,
                                      Wt1T, Wt2T, w1bf, w2bf, wpx, wpy, wpz,
                                      b1c, cand4);
  fat_kernel<<<2048, 256, 0, stream>>>(xyz1, cand4, idxws,
                                       points1, points2, Wt1T, Wt2T,
                                       b1c, b_t22, p1b, p2b);
  fuse_kernel<<<B_ * 1024, 256, 0, stream>>>(xyz1, xyz2, p1b, p2b, idxws,
                                             w1bf, w2bf, wpx, wpy, wpz,
                                             b_mlp1, b_mlp2, out);
}